// Round 6
// baseline (41.263 us; speedup 1.0000x reference)
//
#include <hip/hip_runtime.h>
#include <math.h>

#define F 24
#define D 16
#define BATCH 2048
#define NPAIR 276
#define NTRIP 2024
#define VOCAB 10000
#define NSLOT_TOT 288       // 276 real pairs + 12 zero dummies (exact +0.0)
#define SLOTF 28            // floats per slot: [i, j, g2, pad, c0..c23]

// ---- compile-time index algebra for lexicographic combinations ----
__host__ __device__ constexpr int pair_base(int i) { return i * 23 - i * (i - 1) / 2; }
__host__ __device__ constexpr int trip_base(int i) {
    return NTRIP - (24 - i) * (23 - i) * (22 - i) / 6;
}
__host__ __device__ constexpr int trip_idx(int i, int j, int k) {
    return trip_base(i) + (j - i - 1) * (46 - i - j) / 2 + (k - j - 1);
}

// ---- prep: repack g2/g3 into 288 uniform consumption-order slots ----
__global__ void repack_kernel(const float* __restrict__ g2,
                              const float* __restrict__ g3,
                              float* __restrict__ cw) {
    int s = blockIdx.x * blockDim.x + threadIdx.x;
    if (s >= NSLOT_TOT) return;
    float* o = cw + s * SLOTF;
    for (int t = 0; t < SLOTF; ++t) o[t] = 0.f;     // dummies contribute exactly 0
    if (s < NPAIR) {
        int i = 0;
        while (pair_base(i + 1) <= s) ++i;
        int j = i + 1 + (s - pair_base(i));
        o[0] = __int_as_float(i);
        o[1] = __int_as_float(j);
        o[2] = g2[s];
        if (j < 23) {
            int tb = trip_idx(i, j, j + 1);          // contiguous trip ids
            for (int k = j + 1; k < F; ++k) o[4 + k] = g3[tb + (k - j - 1)];
        }
    }
}

// Block = 256 thr = 4 waves = ONE row. Lanes: d = tid&15, sg = (tid>>4)&3.
// 16-lane group (w*4+sg) owns 18 slots -> 16 groups x 18 = 288 slots/row.
// 2048 blocks, 8192 waves -> 32 waves/CU (8/SIMD) fully resident, one round.
__global__ __launch_bounds__(256, 8) void ctr_main(
    const int* __restrict__ x, const float* __restrict__ emb,
    const float* __restrict__ lw, const float* __restrict__ lb,
    const float* __restrict__ cw, float* __restrict__ out) {
    __shared__ float s_e[F * D];        // [f*16 + d]
    __shared__ int   s_idx[F];
    __shared__ float s_lw[F];
    __shared__ float s_part[16];

    const int tid = threadIdx.x;
    const int row = blockIdx.x;

    if (tid < F) {                      // 24 index + linear-weight gathers
        int idx = x[row * F + tid] + tid * VOCAB;
        s_idx[tid] = idx;
        s_lw[tid] = lw[idx];
    }
    __syncthreads();

    if (tid < F * 4) {                  // 96 float4 gathers: emb row f -> s_e[f*16..]
        int f = tid >> 2, q = tid & 3;
        float4 v = reinterpret_cast<const float4*>(emb)[s_idx[f] * 4 + q];
        float* b = &s_e[f * D + q * 4];
        b[0] = v.x; b[1] = v.y; b[2] = v.z; b[3] = v.w;
    }
    __syncthreads();

    const int d = tid & 15;
    const int sg = (tid >> 4) & 3;
    const int w = tid >> 6;
    // slot-chunk id, wave-uniform per 16-lane group; base made SGPR-friendly
    const int chunk = w * 4 + sg;
    const float* se = s_e;

    float e[F];                          // register copy, statically indexed only
#pragma unroll
    for (int f = 0; f < F; ++f) e[f] = se[f * D + d];

    const float4* cp = reinterpret_cast<const float4*>(cw) + chunk * (18 * 7);
    float acc = 0.f;
#pragma unroll 1
    for (int s = 0; s < 18; ++s) {
        float4 h  = cp[s * 7 + 0];
        float4 c0 = cp[s * 7 + 1], c1 = cp[s * 7 + 2], c2 = cp[s * 7 + 3];
        float4 c3 = cp[s * 7 + 4], c4 = cp[s * 7 + 5], c5 = cp[s * 7 + 6];
        int i = __float_as_int(h.x), j = __float_as_int(h.y);
        float ei = se[i * D + d];        // runtime index -> LDS (2 reads/slot)
        float ej = se[j * D + d];
        // zero-padded 24-term dot: c[k]=g3[ijk] for k>j else 0 (FP-exact zeros)
        float ta = h.z, tb = 0.f;        // ta seeded with g2; two chains for ILP
        ta = fmaf(c0.x, e[0],  ta); tb = fmaf(c0.y, e[1],  tb);
        ta = fmaf(c0.z, e[2],  ta); tb = fmaf(c0.w, e[3],  tb);
        ta = fmaf(c1.x, e[4],  ta); tb = fmaf(c1.y, e[5],  tb);
        ta = fmaf(c1.z, e[6],  ta); tb = fmaf(c1.w, e[7],  tb);
        ta = fmaf(c2.x, e[8],  ta); tb = fmaf(c2.y, e[9],  tb);
        ta = fmaf(c2.z, e[10], ta); tb = fmaf(c2.w, e[11], tb);
        ta = fmaf(c3.x, e[12], ta); tb = fmaf(c3.y, e[13], tb);
        ta = fmaf(c3.z, e[14], ta); tb = fmaf(c3.w, e[15], tb);
        ta = fmaf(c4.x, e[16], ta); tb = fmaf(c4.y, e[17], tb);
        ta = fmaf(c4.z, e[18], ta); tb = fmaf(c4.w, e[19], tb);
        ta = fmaf(c5.x, e[20], ta); tb = fmaf(c5.y, e[21], tb);
        ta = fmaf(c5.z, e[22], ta); tb = fmaf(c5.w, e[23], tb);
        acc = fmaf(ei * ej, ta + tb, acc);   // pij * (g2 + suffix-dot)
    }

    // reduce over the 16 d-lanes (masks 1,2,4,8 stay within each 16-lane group)
#pragma unroll
    for (int m = 1; m < 16; m <<= 1) acc += __shfl_xor(acc, m, 64);
    if (d == 0) s_part[chunk] = acc;
    __syncthreads();

    if (tid < 16) {                      // combine 16 chunk-partials (wave 0)
        float v = s_part[tid];
#pragma unroll
        for (int m = 1; m < 16; m <<= 1) v += __shfl_xor(v, m, 64);
        if (tid == 0) {
            float lin = lb[0];
#pragma unroll
            for (int f = 0; f < F; ++f) lin += s_lw[f];
            float z = v + lin;
            out[row] = 1.f / (1.f + __expf(-z));
        }
    }
}

extern "C" void kernel_launch(void* const* d_in, const int* in_sizes, int n_in,
                              void* d_out, int out_size, void* d_ws, size_t ws_size,
                              hipStream_t stream) {
    const int*   x   = (const int*)d_in[0];
    const float* emb = (const float*)d_in[1];
    const float* lw  = (const float*)d_in[2];
    const float* lb  = (const float*)d_in[3];
    const float* g2  = (const float*)d_in[4];
    const float* g3  = (const float*)d_in[5];
    float* out = (float*)d_out;
    float* cw  = (float*)d_ws;      // 288 slots x 28 floats = 32 KB

    hipLaunchKernelGGL(repack_kernel, dim3(2), dim3(256), 0, stream, g2, g3, cw);
    hipLaunchKernelGGL(ctr_main, dim3(BATCH), dim3(256), 0, stream,
                       x, emb, lw, lb, cw, out);
}

// Round 7
// 21.864 us; speedup vs baseline: 1.8872x; 1.8872x over previous
//
#include <hip/hip_runtime.h>
#include <math.h>

#define F 24
#define D 16
#define BATCH 2048
#define NPAIR 276
#define NTRIP 2024
#define VOCAB 10000
#define EPAD 28     // floats per (r,d) e-slab: 112B, 16B-aligned, 2-way bank alias max

// ---- compile-time index algebra for lexicographic combinations ----
__host__ __device__ constexpr int pair_base(int i) { return i * 23 - i * (i - 1) / 2; }
__host__ __device__ constexpr int pair_idx(int i, int j) { return pair_base(i) + (j - i - 1); }
__host__ __device__ constexpr int trip_base(int i) {
    return NTRIP - (24 - i) * (23 - i) * (22 - i) / 6;
}
__host__ __device__ constexpr int trip_idx(int i, int j, int k) {
    return trip_base(i) + (j - i - 1) * (46 - i - j) / 2 + (k - j - 1);
}

// 16 contiguous pair-index chunks, balanced by trip count (~126 each)
constexpr int CHUNK_B[17] = {0, 7, 23, 30, 46, 54, 70, 86, 95, 111, 127, 143, 160, 179, 201, 227, 276};

// One chunk, one row, true suffix lengths (no padding waste). Everything
// unrolls: e[] statically indexed (VGPRs), g2/g3 at constexpr offsets from a
// wave-uniform base -> scalar s_load stream, hoisted/pipelined by compiler.
template <int C>
__device__ __forceinline__ float chunk_compute(const float (&e)[F],
                                               const float* __restrict__ g2,
                                               const float* __restrict__ g3) {
    constexpr int P0 = CHUNK_B[C], P1 = CHUNK_B[C + 1];
    float acc = 0.f;
#pragma unroll
    for (int i = 0; i < 23; ++i) {
#pragma unroll
        for (int j = i + 1; j < F; ++j) {
            if (pair_idx(i, j) >= P0 && pair_idx(i, j) < P1) {   // folds at compile time
                float pij = e[i] * e[j];
                acc = fmaf(g2[pair_idx(i, j)], pij, acc);        // 2nd-order
                float s = 0.f;
#pragma unroll
                for (int k = j + 1; k < F; ++k)                  // contiguous trip ids
                    s = fmaf(g3[trip_idx(i, j, k)], e[k], s);
                acc = fmaf(pij, s, acc);                         // 3rd-order
            }
        }
    }
    return acc;
}

// Single dispatch. Block = 1024 thr = 16 waves = 16 chunks x 4 rows.
// Lane: d = tid&15, r = (tid>>4)&3; wave w = chunk id (wave-uniform).
__global__ __launch_bounds__(1024, 4) void ctr_main(
    const int* __restrict__ x, const float* __restrict__ emb,
    const float* __restrict__ lw, const float* __restrict__ lb,
    const float* __restrict__ g2, const float* __restrict__ g3,
    float* __restrict__ out) {
    __shared__ float s_e[4 * D * EPAD];   // [(r*16+d)*28 + f]
    __shared__ int   s_idx[4 * F];
    __shared__ float s_lw[4 * F];
    __shared__ float s_part[16][4];       // [chunk][row]

    const int tid = threadIdx.x;
    const int row0 = blockIdx.x * 4;

    if (tid < 4 * F) {                    // 96 index + linear-weight gathers
        int r = tid / F, f = tid - r * F;
        int idx = x[(row0 + r) * F + f] + f * VOCAB;
        s_idx[tid] = idx;
        s_lw[tid] = lw[idx];
    }
    __syncthreads();

    if (tid < 4 * F * 4) {                // 384 float4 gathers; transpose to [r][d][f]
        int seg = tid >> 2, q = tid & 3;  // q selects dims 4q..4q+3
        int r = seg / F, f = seg - r * F;
        float4 v = reinterpret_cast<const float4*>(emb)[s_idx[seg] * 4 + q];
        s_e[(r * D + q * 4 + 0) * EPAD + f] = v.x;
        s_e[(r * D + q * 4 + 1) * EPAD + f] = v.y;
        s_e[(r * D + q * 4 + 2) * EPAD + f] = v.z;
        s_e[(r * D + q * 4 + 3) * EPAD + f] = v.w;
    }
    __syncthreads();

    const int d = tid & 15;
    const int r = (tid >> 4) & 3;
    const int w = tid >> 6;               // chunk id, wave-uniform

    float e[F];                           // 6x ds_read_b128, statically indexed after
    {
        const float4* se4 = reinterpret_cast<const float4*>(&s_e[(r * D + d) * EPAD]);
#pragma unroll
        for (int n = 0; n < 6; ++n) {
            float4 v = se4[n];
            e[4 * n] = v.x; e[4 * n + 1] = v.y; e[4 * n + 2] = v.z; e[4 * n + 3] = v.w;
        }
    }

    float acc;
    switch (w) {
        case 0:  acc = chunk_compute<0>(e, g2, g3); break;
        case 1:  acc = chunk_compute<1>(e, g2, g3); break;
        case 2:  acc = chunk_compute<2>(e, g2, g3); break;
        case 3:  acc = chunk_compute<3>(e, g2, g3); break;
        case 4:  acc = chunk_compute<4>(e, g2, g3); break;
        case 5:  acc = chunk_compute<5>(e, g2, g3); break;
        case 6:  acc = chunk_compute<6>(e, g2, g3); break;
        case 7:  acc = chunk_compute<7>(e, g2, g3); break;
        case 8:  acc = chunk_compute<8>(e, g2, g3); break;
        case 9:  acc = chunk_compute<9>(e, g2, g3); break;
        case 10: acc = chunk_compute<10>(e, g2, g3); break;
        case 11: acc = chunk_compute<11>(e, g2, g3); break;
        case 12: acc = chunk_compute<12>(e, g2, g3); break;
        case 13: acc = chunk_compute<13>(e, g2, g3); break;
        case 14: acc = chunk_compute<14>(e, g2, g3); break;
        default: acc = chunk_compute<15>(e, g2, g3); break;
    }

    // reduce over the 16 d-lanes (masks stay within each 16-lane group)
#pragma unroll
    for (int m = 1; m < 16; m <<= 1) acc += __shfl_xor(acc, m, 64);
    if (d == 0) s_part[w][r] = acc;
    __syncthreads();

    if (tid < 64) {                       // rr = tid>>4 (row), c = tid&15 (chunk)
        const int rr = tid >> 4, c = tid & 15;
        float v = s_part[c][rr];
#pragma unroll
        for (int m = 1; m < 16; m <<= 1) v += __shfl_xor(v, m, 64);
        if (c == 0) {
            float lin = lb[0];
#pragma unroll
            for (int f = 0; f < F; ++f) lin += s_lw[rr * F + f];
            float z = v + lin;
            out[row0 + rr] = 1.f / (1.f + __expf(-z));
        }
    }
}

extern "C" void kernel_launch(void* const* d_in, const int* in_sizes, int n_in,
                              void* d_out, int out_size, void* d_ws, size_t ws_size,
                              hipStream_t stream) {
    const int*   x   = (const int*)d_in[0];
    const float* emb = (const float*)d_in[1];
    const float* lw  = (const float*)d_in[2];
    const float* lb  = (const float*)d_in[3];
    const float* g2  = (const float*)d_in[4];
    const float* g3  = (const float*)d_in[5];
    float* out = (float*)d_out;

    hipLaunchKernelGGL(ctr_main, dim3(BATCH / 4), dim3(1024), 0, stream,
                       x, emb, lw, lb, g2, g3, out);
}

// Round 8
// 19.740 us; speedup vs baseline: 2.0903x; 1.1076x over previous
//
#include <hip/hip_runtime.h>
#include <math.h>

#define F 24
#define D 16
#define BATCH 2048
#define NPAIR 276
#define NTRIP 2024
#define VOCAB 10000
#define SLAB 392            // floats per row slab [f*16+d]: 2-way bank alias max (free)
#define LONG_SLOTS 80       // 16 waves x 5 (66 real + 14 zero dummies)
#define SHORT_SLOTS 224     // 16 waves x 14 (210 real + 14 zero dummies)
#define LONG_F (LONG_SLOTS * 28)                 // 2240 floats
#define CW_FLOATS (LONG_F + SHORT_SLOTS * 16)    // 5824 floats = 23.3 KB

// ---- compile-time index algebra for lexicographic combinations ----
__host__ __device__ constexpr int pair_base(int i) { return i * 23 - i * (i - 1) / 2; }
__host__ __device__ constexpr int trip_base(int i) {
    return NTRIP - (24 - i) * (23 - i) * (22 - i) / 6;
}
__host__ __device__ constexpr int trip_idx(int i, int j, int k) {
    return trip_base(i) + (j - i - 1) * (46 - i - j) / 2 + (k - j - 1);
}

// ---- prep: repack g2/g3 into 2-tier uniform consumption-order slots ----
// long slot (j<=11), 28 floats: [i, j, g2, 0, c0..c23]   (c_k coef of e[k]; c0,c1 always 0)
// short slot (j>=12), 16 floats: [i, j, g2, c13, c14..c17, c18..c21, c22, c23, 0, 0]
//   (slot[3+m] = coef of e[13+m])
__global__ void repack_kernel(const float* __restrict__ g2,
                              const float* __restrict__ g3,
                              float* __restrict__ cw) {
    const int tid = threadIdx.x;                 // single block of 512
    for (int t = tid; t < CW_FLOATS; t += 512) cw[t] = 0.f;
    __syncthreads();
    if (tid < NPAIR) {
        const int p = tid;
        int i = 0;
        while (pair_base(i + 1) <= p) ++i;
        const int j = i + 1 + (p - pair_base(i));
        if (j <= 11) {                           // long tier: pairs within fields 0..11
            const int rank = i * 11 - i * (i - 1) / 2 + (j - i - 1);   // 0..65
            float* o = cw + rank * 28;
            o[0] = __int_as_float(i); o[1] = __int_as_float(j); o[2] = g2[p];
            for (int k = j + 1; k < F; ++k) o[4 + k] = g3[trip_idx(i, j, k)];
        } else {                                 // short tier: suffix within e[13..23]
            const int rank = (i <= 11) ? (12 * i + (j - 12))
                                       : (144 + (35 - i) * (i - 12) / 2 + (j - i - 1));  // 0..209
            float* o = cw + LONG_F + rank * 16;
            o[0] = __int_as_float(i); o[1] = __int_as_float(j); o[2] = g2[p];
            for (int k = j + 1; k < F; ++k) o[k - 10] = g3[trip_idx(i, j, k)];
        }
    }
}

// Block = 1024 thr = 16 waves x (16 d x 4 rows). Wave w (SGPR via readfirstlane)
// owns long slots [5w,5w+5) and short slots [14w,14w+14): identical uniform body
// for every wave, coefficient stream on the scalar pipe (s_load).
__global__ __launch_bounds__(1024, 4) void ctr_main(
    const int* __restrict__ x, const float* __restrict__ emb,
    const float* __restrict__ lw, const float* __restrict__ lb,
    const float* __restrict__ cw, float* __restrict__ out) {
    __shared__ float s_e[4 * SLAB];       // [r][f*16 + d]
    __shared__ int   s_idx[4 * F];
    __shared__ float s_lw[4 * F];
    __shared__ float s_part[16][4];       // [chunk][row]

    const int tid = threadIdx.x;
    const int row0 = blockIdx.x * 4;

    if (tid < 4 * F) {                    // 96 index + linear-weight gathers
        int r = tid / F, f = tid - r * F;
        int idx = x[(row0 + r) * F + f] + f * VOCAB;
        s_idx[tid] = idx;
        s_lw[tid] = lw[idx];
    }
    __syncthreads();

    if (tid < 4 * F * 4) {                // 384 float4 gathers: emb -> LDS [r][f*16+d]
        int seg = tid >> 2, q = tid & 3;
        int r = seg / F, f = seg - r * F;
        float4 v = reinterpret_cast<const float4*>(emb)[s_idx[seg] * 4 + q];
        float* b = &s_e[r * SLAB + f * D + q * 4];
        b[0] = v.x; b[1] = v.y; b[2] = v.z; b[3] = v.w;
    }
    __syncthreads();

    const int d = tid & 15;
    const int r = (tid >> 4) & 3;
    const int w = __builtin_amdgcn_readfirstlane(tid >> 6);   // SGPR chunk id
    const float* se = &s_e[r * SLAB];

    float e[F];                           // register copy, statically indexed only
#pragma unroll
    for (int f = 0; f < F; ++f) e[f] = se[f * D + d];

    float acc = 0.f;

    const float4* Lp = reinterpret_cast<const float4*>(cw) + w * (5 * 7);
#pragma unroll 2
    for (int s = 0; s < 5; ++s) {         // long tier: 22-FMA absolute dot
        float4 h  = Lp[s * 7 + 0];
        float4 c0 = Lp[s * 7 + 1], c1 = Lp[s * 7 + 2], c2 = Lp[s * 7 + 3];
        float4 c3 = Lp[s * 7 + 4], c4 = Lp[s * 7 + 5], c5 = Lp[s * 7 + 6];
        int i = __float_as_int(h.x), j = __float_as_int(h.y);
        float ei = se[i * D + d];         // runtime index -> LDS (2-way alias, free)
        float ej = se[j * D + d];
        float ta = h.z, tb = 0.f;         // seeded with g2; two chains for ILP
        ta = fmaf(c0.z, e[2],  ta); tb = fmaf(c0.w, e[3],  tb);   // c0,c1 == 0 always
        ta = fmaf(c1.x, e[4],  ta); tb = fmaf(c1.y, e[5],  tb);
        ta = fmaf(c1.z, e[6],  ta); tb = fmaf(c1.w, e[7],  tb);
        ta = fmaf(c2.x, e[8],  ta); tb = fmaf(c2.y, e[9],  tb);
        ta = fmaf(c2.z, e[10], ta); tb = fmaf(c2.w, e[11], tb);
        ta = fmaf(c3.x, e[12], ta); tb = fmaf(c3.y, e[13], tb);
        ta = fmaf(c3.z, e[14], ta); tb = fmaf(c3.w, e[15], tb);
        ta = fmaf(c4.x, e[16], ta); tb = fmaf(c4.y, e[17], tb);
        ta = fmaf(c4.z, e[18], ta); tb = fmaf(c4.w, e[19], tb);
        ta = fmaf(c5.x, e[20], ta); tb = fmaf(c5.y, e[21], tb);
        ta = fmaf(c5.z, e[22], ta); tb = fmaf(c5.w, e[23], tb);
        acc = fmaf(ei * ej, ta + tb, acc);
    }

    const float4* Sp = reinterpret_cast<const float4*>(cw) + (LONG_F / 4) + w * (14 * 4);
#pragma unroll 2
    for (int s = 0; s < 14; ++s) {        // short tier: 11-FMA dot over e[13..23]
        float4 h  = Sp[s * 4 + 0];
        float4 k0 = Sp[s * 4 + 1], k1 = Sp[s * 4 + 2], k2 = Sp[s * 4 + 3];
        int i = __float_as_int(h.x), j = __float_as_int(h.y);
        float ei = se[i * D + d];
        float ej = se[j * D + d];
        float ta = h.z, tb = 0.f;
        ta = fmaf(h.w,  e[13], ta);
        tb = fmaf(k0.x, e[14], tb); ta = fmaf(k0.y, e[15], ta);
        tb = fmaf(k0.z, e[16], tb); ta = fmaf(k0.w, e[17], ta);
        tb = fmaf(k1.x, e[18], tb); ta = fmaf(k1.y, e[19], ta);
        tb = fmaf(k1.z, e[20], tb); ta = fmaf(k1.w, e[21], ta);
        tb = fmaf(k2.x, e[22], tb); ta = fmaf(k2.y, e[23], ta);
        acc = fmaf(ei * ej, ta + tb, acc);
    }

    // reduce over the 16 d-lanes (masks stay within each 16-lane group)
#pragma unroll
    for (int m = 1; m < 16; m <<= 1) acc += __shfl_xor(acc, m, 64);
    if (d == 0) s_part[w][r] = acc;
    __syncthreads();

    if (tid < 64) {                       // rr = row, c = chunk (in lane bits 0..3)
        const int rr = tid >> 4, c = tid & 15;
        float v = s_part[c][rr];
#pragma unroll
        for (int m = 1; m < 16; m <<= 1) v += __shfl_xor(v, m, 64);
        if (c == 0) {
            float lin = lb[0];
#pragma unroll
            for (int f = 0; f < F; ++f) lin += s_lw[rr * F + f];
            float z = v + lin;
            out[row0 + rr] = 1.f / (1.f + __expf(-z));
        }
    }
}

extern "C" void kernel_launch(void* const* d_in, const int* in_sizes, int n_in,
                              void* d_out, int out_size, void* d_ws, size_t ws_size,
                              hipStream_t stream) {
    const int*   x   = (const int*)d_in[0];
    const float* emb = (const float*)d_in[1];
    const float* lw  = (const float*)d_in[2];
    const float* lb  = (const float*)d_in[3];
    const float* g2  = (const float*)d_in[4];
    const float* g3  = (const float*)d_in[5];
    float* out = (float*)d_out;
    float* cw  = (float*)d_ws;            // 2-tier slot table, 23.3 KB

    hipLaunchKernelGGL(repack_kernel, dim3(1), dim3(512), 0, stream, g2, g3, cw);
    hipLaunchKernelGGL(ctr_main, dim3(BATCH / 4), dim3(1024), 0, stream,
                       x, emb, lw, lb, cw, out);
}

// Round 9
// 17.148 us; speedup vs baseline: 2.4062x; 1.1512x over previous
//
#include <hip/hip_runtime.h>
#include <math.h>

#define F 24
#define D 16
#define BATCH 2048
#define NPAIR 276
#define NTRIP 2024
#define VOCAB 10000
#define SLAB 392            // floats per row slab [f*16+d]: 2-way bank alias max (free)
#define LONG_SLOTS 80       // 16 waves x 5 (66 real + 14 zero dummies)
#define SHORT_SLOTS 224     // 16 waves x 14 (210 real + 14 zero dummies)
#define LONG_F (LONG_SLOTS * 28)                 // 2240 floats
#define CW_FLOATS (LONG_F + SHORT_SLOTS * 16)    // 5824 floats = 23.3 KB

// ---- index algebra for lexicographic combinations ----
__host__ __device__ constexpr int pair_base(int i) { return i * 23 - i * (i - 1) / 2; }
__host__ __device__ constexpr int trip_base(int i) {
    return NTRIP - (24 - i) * (23 - i) * (22 - i) / 6;
}
__host__ __device__ constexpr int trip_idx(int i, int j, int k) {
    return trip_base(i) + (j - i - 1) * (46 - i - j) / 2 + (k - j - 1);
}
// long tier: pairs with j<=11, rank base per i
__device__ __forceinline__ int lbase(int i) { return 11 * i - i * (i - 1) / 2; }
// short tier: pairs with j>=12; ranks 0..143 are i<=11 (12 per i), then triangular
__device__ __forceinline__ int sbase(int i) { return 144 + (35 - i) * (i - 12) / 2; }

// ---- prep: fully parallel repack, ONE THREAD PER OUTPUT FLOAT (~0.5 us) ----
// long slot (j<=11), 28 floats: [i, j, g2, 0, c0..c23]  (c_k = coef of e[k])
// short slot (j>=12), 16 floats: [i, j, g2, c13..c23, 0, 0] (field 3+m = coef e[13+m])
__global__ __launch_bounds__(256) void repack_kernel(const float* __restrict__ g2,
                                                     const float* __restrict__ g3,
                                                     float* __restrict__ cw) {
    const int t = blockIdx.x * 256 + threadIdx.x;
    if (t >= CW_FLOATS) return;
    float v = 0.f;
    if (t < LONG_F) {
        const int slot = t / 28, field = t - slot * 28;
        if (slot < 66) {                          // real long slot
            int i = 0;
            while (lbase(i + 1) <= slot) ++i;     // i in 0..10
            const int j = i + 1 + (slot - lbase(i));
            if (field == 0) v = __int_as_float(i);
            else if (field == 1) v = __int_as_float(j);
            else if (field == 2) v = g2[pair_base(i) + (j - i - 1)];
            else if (field >= 4) {
                const int k = field - 4;
                if (k > j) v = g3[trip_idx(i, j, k)];
            }
        }
    } else {
        const int tt = t - LONG_F;
        const int slot = tt / 16, field = tt - slot * 16;
        if (slot < 210) {                         // real short slot
            int i, j;
            if (slot < 144) { i = slot / 12; j = 12 + (slot - 12 * i); }
            else { i = 12; while (sbase(i + 1) <= slot) ++i; j = i + 1 + (slot - sbase(i)); }
            if (field == 0) v = __int_as_float(i);
            else if (field == 1) v = __int_as_float(j);
            else if (field == 2) v = g2[pair_base(i) + (j - i - 1)];
            else if (field >= 3 && field <= 13) {
                const int k = 10 + field;         // e[13]..e[23]
                if (k > j) v = g3[trip_idx(i, j, k)];
            }
        }
    }
    cw[t] = v;
}

// Block = 1024 thr = 16 waves x (16 d x 4 rows). Wave w (SGPR) owns long slots
// [5w,5w+5) and short slots [14w,14w+14). Uniform body, scalar coef stream.
// Staging: ONE barrier (each gather thread re-loads its own x scalar).
__global__ __launch_bounds__(1024, 4) void ctr_main(
    const int* __restrict__ x, const float* __restrict__ emb,
    const float* __restrict__ lw, const float* __restrict__ lb,
    const float* __restrict__ cw, float* __restrict__ out) {
    __shared__ float s_e[4 * SLAB];       // [r][f*16 + d]
    __shared__ float s_lw[4 * F];
    __shared__ float s_part[16][4];       // [chunk][row]

    const int tid = threadIdx.x;
    const int row0 = blockIdx.x * 4;

    if (tid < 4 * F * 4) {                // 384 thr: emb gather, own x load, 1 round
        const int seg = tid >> 2, q = tid & 3;
        const int r = seg / F, f = seg - r * F;
        const int idx = x[(row0 + r) * F + f] + f * VOCAB;
        float4 v = reinterpret_cast<const float4*>(emb)[idx * 4 + q];
        float* b = &s_e[r * SLAB + f * D + q * 4];
        b[0] = v.x; b[1] = v.y; b[2] = v.z; b[3] = v.w;
    } else if (tid < 4 * F * 4 + 4 * F) { // 96 thr: linear-weight gather, own x load
        const int tt = tid - 4 * F * 4;
        const int r = tt / F, f = tt - r * F;
        s_lw[tt] = lw[x[(row0 + r) * F + f] + f * VOCAB];
    }
    __syncthreads();

    const int d = tid & 15;
    const int r = (tid >> 4) & 3;
    const int w = __builtin_amdgcn_readfirstlane(tid >> 6);   // SGPR chunk id
    const float* se = &s_e[r * SLAB];

    float e[F];                           // register copy, statically indexed only
#pragma unroll
    for (int f = 0; f < F; ++f) e[f] = se[f * D + d];

    float acc = 0.f;

    const float4* Lp = reinterpret_cast<const float4*>(cw) + w * (5 * 7);
#pragma unroll 2
    for (int s = 0; s < 5; ++s) {         // long tier: 22-FMA absolute dot
        float4 h  = Lp[s * 7 + 0];
        float4 c0 = Lp[s * 7 + 1], c1 = Lp[s * 7 + 2], c2 = Lp[s * 7 + 3];
        float4 c3 = Lp[s * 7 + 4], c4 = Lp[s * 7 + 5], c5 = Lp[s * 7 + 6];
        int i = __float_as_int(h.x), j = __float_as_int(h.y);
        float ei = se[i * D + d];         // runtime index -> LDS (2-way alias, free)
        float ej = se[j * D + d];
        float ta = h.z, tb = 0.f;         // seeded with g2; two chains for ILP
        ta = fmaf(c0.z, e[2],  ta); tb = fmaf(c0.w, e[3],  tb);   // c0,c1 == 0 always
        ta = fmaf(c1.x, e[4],  ta); tb = fmaf(c1.y, e[5],  tb);
        ta = fmaf(c1.z, e[6],  ta); tb = fmaf(c1.w, e[7],  tb);
        ta = fmaf(c2.x, e[8],  ta); tb = fmaf(c2.y, e[9],  tb);
        ta = fmaf(c2.z, e[10], ta); tb = fmaf(c2.w, e[11], tb);
        ta = fmaf(c3.x, e[12], ta); tb = fmaf(c3.y, e[13], tb);
        ta = fmaf(c3.z, e[14], ta); tb = fmaf(c3.w, e[15], tb);
        ta = fmaf(c4.x, e[16], ta); tb = fmaf(c4.y, e[17], tb);
        ta = fmaf(c4.z, e[18], ta); tb = fmaf(c4.w, e[19], tb);
        ta = fmaf(c5.x, e[20], ta); tb = fmaf(c5.y, e[21], tb);
        ta = fmaf(c5.z, e[22], ta); tb = fmaf(c5.w, e[23], tb);
        acc = fmaf(ei * ej, ta + tb, acc);
    }

    const float4* Sp = reinterpret_cast<const float4*>(cw) + (LONG_F / 4) + w * (14 * 4);
#pragma unroll 2
    for (int s = 0; s < 14; ++s) {        // short tier: 11-FMA dot over e[13..23]
        float4 h  = Sp[s * 4 + 0];
        float4 k0 = Sp[s * 4 + 1], k1 = Sp[s * 4 + 2], k2 = Sp[s * 4 + 3];
        int i = __float_as_int(h.x), j = __float_as_int(h.y);
        float ei = se[i * D + d];
        float ej = se[j * D + d];
        float ta = h.z, tb = 0.f;
        ta = fmaf(h.w,  e[13], ta);
        tb = fmaf(k0.x, e[14], tb); ta = fmaf(k0.y, e[15], ta);
        tb = fmaf(k0.z, e[16], tb); ta = fmaf(k0.w, e[17], ta);
        tb = fmaf(k1.x, e[18], tb); ta = fmaf(k1.y, e[19], ta);
        tb = fmaf(k1.z, e[20], tb); ta = fmaf(k1.w, e[21], ta);
        tb = fmaf(k2.x, e[22], tb); ta = fmaf(k2.y, e[23], ta);
        acc = fmaf(ei * ej, ta + tb, acc);
    }

    // reduce over the 16 d-lanes (masks stay within each 16-lane group)
#pragma unroll
    for (int m = 1; m < 16; m <<= 1) acc += __shfl_xor(acc, m, 64);
    if (d == 0) s_part[w][r] = acc;
    __syncthreads();

    if (tid < 64) {                       // rr = row, c = chunk (in lane bits 0..3)
        const int rr = tid >> 4, c = tid & 15;
        float v = s_part[c][rr];
#pragma unroll
        for (int m = 1; m < 16; m <<= 1) v += __shfl_xor(v, m, 64);
        if (c == 0) {
            float lin = lb[0];
#pragma unroll
            for (int f = 0; f < F; ++f) lin += s_lw[rr * F + f];
            float z = v + lin;
            out[row0 + rr] = 1.f / (1.f + __expf(-z));
        }
    }
}

extern "C" void kernel_launch(void* const* d_in, const int* in_sizes, int n_in,
                              void* d_out, int out_size, void* d_ws, size_t ws_size,
                              hipStream_t stream) {
    const int*   x   = (const int*)d_in[0];
    const float* emb = (const float*)d_in[1];
    const float* lw  = (const float*)d_in[2];
    const float* lb  = (const float*)d_in[3];
    const float* g2  = (const float*)d_in[4];
    const float* g3  = (const float*)d_in[5];
    float* out = (float*)d_out;
    float* cw  = (float*)d_ws;            // 2-tier slot table, 23.3 KB

    hipLaunchKernelGGL(repack_kernel, dim3((CW_FLOATS + 255) / 256), dim3(256), 0, stream,
                       g2, g3, cw);
    hipLaunchKernelGGL(ctr_main, dim3(BATCH / 4), dim3(1024), 0, stream,
                       x, emb, lw, lb, cw, out);
}